// Round 5
// baseline (162.725 us; speedup 1.0000x reference)
//
#include <hip/hip_runtime.h>
#include <hip/hip_bf16.h>

#define B_ 16
#define N_ 512
#define F_ 32
#define T_ 24
#define K_ 3
#define C_ 64
#define FT_ 768   // F_*T_
#define KF_ 96    // K_*F_

typedef __attribute__((ext_vector_type(8))) short bf16x8;
typedef __attribute__((ext_vector_type(4))) float f32x4;

static __device__ __forceinline__ ushort f2b(float x) {
  uint u = __float_as_uint(x);
  return (ushort)((u + 0x7fffu + ((u >> 16) & 1u)) >> 16);
}
static __device__ __forceinline__ uint pk2(float a, float b) {
  return (uint)f2b(a) | ((uint)f2b(b) << 16);
}

#define GLOAD_LDS16(g, l)                                                     \
  __builtin_amdgcn_global_load_lds(                                           \
      (const __attribute__((address_space(1))) void*)(g),                     \
      (__attribute__((address_space(3))) void*)(l), 16, 0, 0)

// ---------------- prep kernels ----------------

// Xt2[b][t*32+f][n] (bf16) = X[b][n][f*24+t]
// grid: (48, 16): gx%16 -> n-chunk of 32, gx/16 -> ft-group of 256 (t-range 8)
#define XP_PAD 260
__global__ __launch_bounds__(256) void prepX(const float* __restrict__ X,
                                             ushort* __restrict__ Xt2) {
  __shared__ ushort L[32 * XP_PAD];  // [n_local][f*8+dt], padded
  const int b = blockIdx.y;
  const int n0 = (blockIdx.x & 15) * 32;
  const int fg = blockIdx.x >> 4;          // 0..2, t in [fg*8, fg*8+8)
  const int tid = threadIdx.x;

  const float* Xp = X + ((size_t)b * N_ + n0) * FT_ + fg * 8;
  // stage the needed 32 rows x (32 f-runs x 8 t) slice, bf16-packed
#pragma unroll
  for (int it = 0; it < 8; ++it) {
    int c = tid + it * 256;                // 2048 float4 chunks
    int row = c >> 6, rem = c & 63;
    int f = rem >> 1, half = rem & 1;
    float4 v = *(const float4*)(Xp + (size_t)row * FT_ + f * 24 + half * 4);
    uint2 p; p.x = pk2(v.x, v.y); p.y = pk2(v.z, v.w);
    *(uint2*)&L[row * XP_PAD + f * 8 + half * 4] = p;
  }
  __syncthreads();
  // each thread emits one output row ft2 = fg*256 + tid
  const int ft2 = fg * 256 + tid;
  const int f = tid & 31, dt = tid >> 5;
  ushort a[32];
#pragma unroll
  for (int r = 0; r < 32; ++r) a[r] = L[r * XP_PAD + f * 8 + dt];
  uint w[16];
#pragma unroll
  for (int q = 0; q < 16; ++q) w[q] = (uint)a[2 * q] | ((uint)a[2 * q + 1] << 16);
  ushort* op = Xt2 + ((size_t)b * FT_ + ft2) * N_ + n0;
#pragma unroll
  for (int q = 0; q < 4; ++q) {
    uint4 v; v.x = w[4*q]; v.y = w[4*q+1]; v.z = w[4*q+2]; v.w = w[4*q+3];
    *((uint4*)op + q) = v;
  }
}

// At[k*16+b][m][n] (bf16) = CH[k][n][m] * SA[b][n][m]   (n<->m transpose)
__global__ __launch_bounds__(256) void prepA(const float* __restrict__ SA,
                                             const float* __restrict__ CH,
                                             ushort* __restrict__ At) {
  const int kb = blockIdx.y;
  const int k = kb >> 4, b = kb & 15;
  const int m0 = (blockIdx.x & 7) * 64, n0 = (blockIdx.x >> 3) * 64;
  const int tid = threadIdx.x;
  const int ml = (tid & 15) * 4, nl = (tid >> 4) * 4;

  const float* cp = CH + ((size_t)k * N_ + n0 + nl) * N_ + m0 + ml;
  const float* sp = SA + ((size_t)b * N_ + n0 + nl) * N_ + m0 + ml;
  float4 p[4];
#pragma unroll
  for (int q = 0; q < 4; ++q) {
    float4 c = *(const float4*)(cp + (size_t)q * N_);
    float4 s = *(const float4*)(sp + (size_t)q * N_);
    p[q] = make_float4(c.x * s.x, c.y * s.y, c.z * s.z, c.w * s.w);
  }
  ushort* ob = At + (size_t)kb * N_ * N_ + (size_t)(m0 + ml) * N_ + n0 + nl;
#pragma unroll
  for (int s = 0; s < 4; ++s) {
    uint2 w;
    w.x = pk2(((const float*)&p[0])[s], ((const float*)&p[1])[s]);
    w.y = pk2(((const float*)&p[2])[s], ((const float*)&p[3])[s]);
    *(uint2*)(ob + (size_t)s * N_) = w;
  }
}

// ---------------- stage 1: GEMM, 2-phase dbuf + T2 swizzle ----------------
// R2[b][t][m][k*32+f] = sum_n Xt2[b][t*32+f][n] * At[k*16+b][m][n]
__global__ __launch_bounds__(256, 2) void stage1(const ushort* __restrict__ Xt2,
                                                 const ushort* __restrict__ At,
                                                 ushort* __restrict__ R2) {
  __shared__ __align__(16) ushort Abuf[2][128 * 64];
  __shared__ __align__(16) ushort Bbuf[2][128 * 64];
  const int kb = blockIdx.y;
  const int k = kb >> 4, b = kb & 15;
  const int ft0 = (blockIdx.x >> 2) * 128;
  const int m0 = (blockIdx.x & 3) * 128;
  const int tid = threadIdx.x, lane = tid & 63, wid = tid >> 6;
  const int wft = (wid >> 1) * 64, wm = (wid & 1) * 64;

  const char* Xbase = (const char*)(Xt2 + ((size_t)b * FT_ + ft0) * N_);
  const char* Bbase = (const char*)(At + ((size_t)kb * N_ + m0) * N_);
  const int srow = lane >> 3;                       // 0..7
  const int scolS = ((lane & 7) * 16) ^ (srow << 4); // pre-swizzled source col

  f32x4 acc[4][4];
#pragma unroll
  for (int i = 0; i < 4; ++i)
#pragma unroll
    for (int j = 0; j < 4; ++j) acc[i][j] = (f32x4){0.f, 0.f, 0.f, 0.f};

  // LDS[row][c] = G[row][c ^ ((row&7)<<4)]  (involution, both-sides swizzle)
#define STAGE1_LOAD(bufi, nb)                                                  \
  {                                                                            \
    _Pragma("unroll")                                                          \
    for (int c = 0; c < 4; ++c) {                                              \
      const int s = wid * 4 + c;                                               \
      const size_t go = (size_t)(s * 8 + srow) * 1024 + (nb) * 128 + scolS;    \
      GLOAD_LDS16(Xbase + go, (char*)Abuf[bufi] + s * 1024);                   \
      GLOAD_LDS16(Bbase + go, (char*)Bbuf[bufi] + s * 1024);                   \
    }                                                                          \
  }

  STAGE1_LOAD(0, 0);
  __syncthreads();

  int cur = 0;
  for (int nb = 0; nb < 8; ++nb) {
    if (nb < 7) STAGE1_LOAD(cur ^ 1, nb + 1);
    const char* Ab = (const char*)Abuf[cur];
    const char* Bb = (const char*)Bbuf[cur];
#pragma unroll
    for (int kk = 0; kk < 2; ++kk) {
      const int cb = (kk * 64 + (lane >> 4) * 16) ^ ((lane & 7) << 4);
      bf16x8 af[4], bfv[4];
#pragma unroll
      for (int i = 0; i < 4; ++i)
        af[i] = *(const bf16x8*)(Ab + (wft + i * 16 + (lane & 15)) * 128 + cb);
#pragma unroll
      for (int j = 0; j < 4; ++j)
        bfv[j] = *(const bf16x8*)(Bb + (wm + j * 16 + (lane & 15)) * 128 + cb);
#pragma unroll
      for (int i = 0; i < 4; ++i)
#pragma unroll
        for (int j = 0; j < 4; ++j)
          acc[i][j] = __builtin_amdgcn_mfma_f32_16x16x32_bf16(af[i], bfv[j], acc[i][j], 0, 0, 0);
    }
    __syncthreads();   // drains vmcnt(0): buf^1 staged; all reads of buf done
    cur ^= 1;
  }

  // epilogue: D row=(lane>>4)*4+reg (ft local), col=lane&15 (m); pack 4 f -> 8B
  const int col = lane & 15, rg4 = (lane >> 4) * 4;
#pragma unroll
  for (int i = 0; i < 4; ++i) {
    const int ft2 = ft0 + wft + i * 16 + rg4;
    const int t = ft2 >> 5, f = ft2 & 31;
#pragma unroll
    for (int j = 0; j < 4; ++j) {
      const int m = m0 + wm + j * 16 + col;
      uint2 w;
      w.x = pk2(acc[i][j][0], acc[i][j][1]);
      w.y = pk2(acc[i][j][2], acc[i][j][3]);
      *(uint2*)(R2 + ((size_t)(b * T_ + t) * N_ + m) * KF_ + k * 32 + f) = w;
    }
  }
}

// ---------------- stage 2: out = relu(R2 x Theta), MFMA, no LDS ----------------
__global__ __launch_bounds__(256, 2) void stage2(const ushort* __restrict__ R2,
                                                 const float* __restrict__ TH,
                                                 float* __restrict__ Out) {
  const int mh = blockIdx.x;   // 0..1
  const int t = blockIdx.y, b = blockIdx.z;
  const int tid = threadIdx.x, lane = tid & 63, wid = tid >> 6;
  const int m0w = mh * 256 + wid * 64;
  const int col = lane & 15, kc = (lane >> 4) * 8, rg4 = (lane >> 4) * 4;

  // B-frag: lane holds Theta[kf = ks*32+kc .. +7][o = j*16+col] as bf16
  bf16x8 bfr[3][4];
#pragma unroll
  for (int ks = 0; ks < 3; ++ks)
#pragma unroll
    for (int j = 0; j < 4; ++j) {
      const float* tp = TH + (size_t)(ks * 32 + kc) * C_ + j * 16 + col;
      bf16x8 v;
#pragma unroll
      for (int q = 0; q < 8; ++q) v[q] = (short)f2b(tp[(size_t)q * C_]);
      bfr[ks][j] = v;
    }

  const ushort* Rb = R2 + ((size_t)b * T_ + t) * N_ * KF_;
  float* Ob = Out + ((size_t)t * B_ + b) * N_ * C_;

#pragma unroll
  for (int i = 0; i < 4; ++i) {
    const int m = m0w + i * 16;
    bf16x8 af[3];
#pragma unroll
    for (int ks = 0; ks < 3; ++ks)
      af[ks] = *(const bf16x8*)(Rb + (size_t)(m + col) * KF_ + ks * 32 + kc);
    f32x4 acc[4];
#pragma unroll
    for (int j = 0; j < 4; ++j) acc[j] = (f32x4){0.f, 0.f, 0.f, 0.f};
#pragma unroll
    for (int ks = 0; ks < 3; ++ks)
#pragma unroll
      for (int j = 0; j < 4; ++j)
        acc[j] = __builtin_amdgcn_mfma_f32_16x16x32_bf16(af[ks], bfr[ks][j], acc[j], 0, 0, 0);
#pragma unroll
    for (int j = 0; j < 4; ++j)
#pragma unroll
      for (int r = 0; r < 4; ++r)
        Ob[(size_t)(m + rg4 + r) * C_ + j * 16 + col] = fmaxf(acc[j][r], 0.f);
  }
}

extern "C" void kernel_launch(void* const* d_in, const int* in_sizes, int n_in,
                              void* d_out, int out_size, void* d_ws, size_t ws_size,
                              hipStream_t stream) {
  const float* X  = (const float*)d_in[0];  // [16,512,32,24]
  const float* SA = (const float*)d_in[1];  // [16,512,512]
  const float* CH = (const float*)d_in[2];  // [3,512,512]
  const float* TH = (const float*)d_in[3];  // [3,32,64]
  float* Out = (float*)d_out;               // [24,16,512,64]

  // ws partition (bytes): R2 37,748,736 | Xt2 12,582,912 | At 25,165,824
  char* ws = (char*)d_ws;
  ushort* R2  = (ushort*)(ws);
  ushort* Xt2 = (ushort*)(ws + 37748736);
  ushort* At  = (ushort*)(ws + 37748736 + 12582912);

  prepX<<<dim3(48, 16), 256, 0, stream>>>(X, Xt2);
  prepA<<<dim3(64, 48), 256, 0, stream>>>(SA, CH, At);
  stage1<<<dim3(24, 48), 256, 0, stream>>>(Xt2, At, R2);
  stage2<<<dim3(2, 24, 16), 256, 0, stream>>>(R2, TH, Out);
}

// Round 6
// 145.456 us; speedup vs baseline: 1.1187x; 1.1187x over previous
//
#include <hip/hip_runtime.h>
#include <hip/hip_bf16.h>

#define B_ 16
#define N_ 512
#define F_ 32
#define T_ 24
#define K_ 3
#define C_ 64
#define FT_ 768   // F_*T_
#define KF_ 96    // K_*F_

typedef __attribute__((ext_vector_type(8))) short bf16x8;
typedef __attribute__((ext_vector_type(4))) float f32x4;

static __device__ __forceinline__ ushort f2b(float x) {
  uint u = __float_as_uint(x);
  return (ushort)((u + 0x7fffu + ((u >> 16) & 1u)) >> 16);
}
static __device__ __forceinline__ uint pk2(float a, float b) {
  return (uint)f2b(a) | ((uint)f2b(b) << 16);
}

#define GLOAD_LDS16(g, l)                                                     \
  __builtin_amdgcn_global_load_lds(                                           \
      (const __attribute__((address_space(1))) void*)(g),                     \
      (__attribute__((address_space(3))) void*)(l), 16, 0, 0)

// ---------------- merged prep: X-transpose (blocks 0..767) + A-build (768..1535)
#define XP_PAD 260
__global__ __launch_bounds__(256) void prep(const float* __restrict__ X,
                                            const float* __restrict__ SA,
                                            const float* __restrict__ CH,
                                            ushort* __restrict__ Xt2,
                                            ushort* __restrict__ At) {
  __shared__ ushort L[32 * XP_PAD];
  const int bid = blockIdx.x;
  const int tid = threadIdx.x;
  if (bid < 768) {
    // Xt2[b][t*32+f][n] = X[b][n][f*24+t]
    const int local = bid % 48;
    const int b = bid / 48;
    const int n0 = (local & 15) * 32;
    const int fg = local >> 4;             // t in [fg*8, fg*8+8)
    const float* Xp = X + ((size_t)b * N_ + n0) * FT_ + fg * 8;
#pragma unroll
    for (int it = 0; it < 8; ++it) {
      int c = tid + it * 256;
      int row = c >> 6, rem = c & 63;
      int f = rem >> 1, half = rem & 1;
      float4 v = *(const float4*)(Xp + (size_t)row * FT_ + f * 24 + half * 4);
      uint2 p; p.x = pk2(v.x, v.y); p.y = pk2(v.z, v.w);
      *(uint2*)&L[row * XP_PAD + f * 8 + half * 4] = p;
    }
    __syncthreads();
    const int ft2 = fg * 256 + tid;
    const int f = tid & 31, dt = tid >> 5;
    ushort a[32];
#pragma unroll
    for (int r = 0; r < 32; ++r) a[r] = L[r * XP_PAD + f * 8 + dt];
    uint w[16];
#pragma unroll
    for (int q = 0; q < 16; ++q) w[q] = (uint)a[2 * q] | ((uint)a[2 * q + 1] << 16);
    ushort* op = Xt2 + ((size_t)b * FT_ + ft2) * N_ + n0;
#pragma unroll
    for (int q = 0; q < 4; ++q) {
      uint4 v; v.x = w[4*q]; v.y = w[4*q+1]; v.z = w[4*q+2]; v.w = w[4*q+3];
      *((uint4*)op + q) = v;
    }
  } else {
    // At[k*16+b][m][n] = CH[k][n][m] * SA[b][n][m]
    const int a = bid - 768;
    const int kb = a >> 4;
    const int k = kb >> 4, b = kb & 15;
    const int sub = a & 15;
    const int ml = (tid & 15) * 4, nl = (tid >> 4) * 4;
#pragma unroll
    for (int c = 0; c < 4; ++c) {
      const int tile = sub * 4 + c;
      const int m0 = (tile & 7) * 64, n0 = (tile >> 3) * 64;
      const float* cp = CH + ((size_t)k * N_ + n0 + nl) * N_ + m0 + ml;
      const float* sp = SA + ((size_t)b * N_ + n0 + nl) * N_ + m0 + ml;
      float4 p[4];
#pragma unroll
      for (int q = 0; q < 4; ++q) {
        float4 cv = *(const float4*)(cp + (size_t)q * N_);
        float4 sv = *(const float4*)(sp + (size_t)q * N_);
        p[q] = make_float4(cv.x * sv.x, cv.y * sv.y, cv.z * sv.z, cv.w * sv.w);
      }
      ushort* ob = At + (size_t)kb * N_ * N_ + (size_t)(m0 + ml) * N_ + n0 + nl;
#pragma unroll
      for (int s = 0; s < 4; ++s) {
        uint2 w;
        w.x = pk2(((const float*)&p[0])[s], ((const float*)&p[1])[s]);
        w.y = pk2(((const float*)&p[2])[s], ((const float*)&p[3])[s]);
        *(uint2*)(ob + (size_t)s * N_) = w;
      }
    }
  }
}

// ---------------- stage 1: k-folded GEMM, 768 blocks (3/CU, all resident) ----
// R2v[((b*24+t)*12 + k*4 + g)*4096 + m*8 + (f&7)] = sum_n Xt2[b][t*32+f][n]*At[k*16+b][m][n]
// block: 128 ft x 64 m x all 3 k; K-loop nb: stage A(16KB)+3xB(8KB), 2x(4af+3x(2bf,8mfma))
__global__ __launch_bounds__(256, 3) void stage1(const ushort* __restrict__ Xt2,
                                                 const ushort* __restrict__ At,
                                                 ushort* __restrict__ R2) {
  __shared__ __align__(16) ushort Abuf[128 * 64];
  __shared__ __align__(16) ushort Bbuf[3][64 * 64];

  const int bid = blockIdx.x;
  const int logical = (bid & 7) * 96 + (bid >> 3);   // XCD-chunked, bijective (768%8==0)
  const int b = logical / 48;
  const int tile = logical % 48;
  const int ft0 = (tile >> 3) * 128;
  const int m0 = (tile & 7) * 64;
  const int tid = threadIdx.x, lane = tid & 63, wid = tid >> 6;
  const int wft = (wid >> 1) * 64, wm = (wid & 1) * 32;
  const int srow = lane >> 3;                         // 0..7
  const int scolS = ((lane & 7) * 16) ^ (srow << 4);  // pre-swizzled source col

  const char* Xbase = (const char*)(Xt2 + ((size_t)b * FT_ + ft0) * N_);
  const char* Bk[3];
#pragma unroll
  for (int kq = 0; kq < 3; ++kq)
    Bk[kq] = (const char*)(At + ((size_t)(kq * 16 + b) * N_ + m0) * N_);

  f32x4 acc[3][4][2];
#pragma unroll
  for (int kq = 0; kq < 3; ++kq)
#pragma unroll
    for (int i = 0; i < 4; ++i)
#pragma unroll
      for (int j = 0; j < 2; ++j) acc[kq][i][j] = (f32x4){0.f, 0.f, 0.f, 0.f};

  for (int nb = 0; nb < 8; ++nb) {
    __syncthreads();
#pragma unroll
    for (int c = 0; c < 4; ++c) {                     // A: 16 segs of 1KB
      const int s = wid * 4 + c;
      const size_t go = (size_t)(s * 8 + srow) * 1024 + nb * 128 + scolS;
      GLOAD_LDS16(Xbase + go, (char*)Abuf + s * 1024);
    }
#pragma unroll
    for (int c = 0; c < 6; ++c) {                     // B: 3 x 8 segs of 1KB
      const int idx = wid * 6 + c;
      const int kq = idx >> 3, seg = idx & 7;
      const size_t go = (size_t)(seg * 8 + srow) * 1024 + nb * 128 + scolS;
      GLOAD_LDS16(Bk[kq] + go, (char*)Bbuf[kq] + seg * 1024);
    }
    __syncthreads();
#pragma unroll
    for (int kk = 0; kk < 2; ++kk) {
      const int cb = (kk * 64 + (lane >> 4) * 16) ^ ((lane & 7) << 4);
      bf16x8 af[4];
#pragma unroll
      for (int i = 0; i < 4; ++i)
        af[i] = *(const bf16x8*)((const char*)Abuf + (wft + i * 16 + (lane & 15)) * 128 + cb);
#pragma unroll
      for (int kq = 0; kq < 3; ++kq) {
        bf16x8 bf[2];
#pragma unroll
        for (int j = 0; j < 2; ++j)
          bf[j] = *(const bf16x8*)((const char*)Bbuf[kq] + (wm + j * 16 + (lane & 15)) * 128 + cb);
#pragma unroll
        for (int i = 0; i < 4; ++i)
#pragma unroll
          for (int j = 0; j < 2; ++j)
            acc[kq][i][j] = __builtin_amdgcn_mfma_f32_16x16x32_bf16(af[i], bf[j], acc[kq][i][j], 0, 0, 0);
      }
    }
  }

  // epilogue: D row=(lane>>4)*4+reg (ft), col=lane&15 (m); R2v packed 8B stores
  const int col = lane & 15, rg4 = (lane >> 4) * 4;
#pragma unroll
  for (int kq = 0; kq < 3; ++kq)
#pragma unroll
    for (int i = 0; i < 4; ++i) {
      const int ft2 = ft0 + wft + i * 16 + rg4;
      const int t = ft2 >> 5, f = ft2 & 31;
      const size_t rowbase = ((size_t)(b * T_ + t) * 12 + kq * 4 + (f >> 3)) * 4096 + (f & 7);
#pragma unroll
      for (int j = 0; j < 2; ++j) {
        const int m = m0 + wm + j * 16 + col;
        uint2 w;
        w.x = pk2(acc[kq][i][j][0], acc[kq][i][j][1]);
        w.y = pk2(acc[kq][i][j][2], acc[kq][i][j][3]);
        *(uint2*)(R2 + rowbase + (size_t)m * 8) = w;
      }
    }
}

// ---------------- stage 2: out = relu(R2v x Theta), MFMA, coalesced, no LDS ---
__global__ __launch_bounds__(256, 2) void stage2(const ushort* __restrict__ R2,
                                                 const float* __restrict__ TH,
                                                 float* __restrict__ Out) {
  const int mh = blockIdx.x;   // 0..1
  const int t = blockIdx.y, b = blockIdx.z;
  const int tid = threadIdx.x, lane = tid & 63, wid = tid >> 6;
  const int m0w = mh * 256 + wid * 64;
  const int col = lane & 15, g = lane >> 4, rg4 = g * 4;

  // B-frag: lane holds Theta[kf = ks*32 + g*8 + q][o = j*16+col]
  bf16x8 bfr[3][4];
#pragma unroll
  for (int ks = 0; ks < 3; ++ks)
#pragma unroll
    for (int j = 0; j < 4; ++j) {
      const float* tp = TH + (size_t)(ks * 32 + g * 8) * C_ + j * 16 + col;
      bf16x8 v;
#pragma unroll
      for (int q = 0; q < 8; ++q) v[q] = (short)f2b(tp[(size_t)q * C_]);
      bfr[ks][j] = v;
    }

  const ushort* Rb = R2 + ((size_t)(b * T_ + t) * 12) * 4096;
  float* Ob = Out + ((size_t)t * B_ + b) * N_ * C_;

#pragma unroll
  for (int i = 0; i < 4; ++i) {
    const int m = m0w + i * 16;
    bf16x8 af[3];
#pragma unroll
    for (int ks = 0; ks < 3; ++ks)
      af[ks] = *(const bf16x8*)(Rb + (size_t)(ks * 4 + g) * 4096 + (size_t)(m + col) * 8);
    f32x4 acc[4];
#pragma unroll
    for (int j = 0; j < 4; ++j) acc[j] = (f32x4){0.f, 0.f, 0.f, 0.f};
#pragma unroll
    for (int ks = 0; ks < 3; ++ks)
#pragma unroll
      for (int j = 0; j < 4; ++j)
        acc[j] = __builtin_amdgcn_mfma_f32_16x16x32_bf16(af[ks], bfr[ks][j], acc[j], 0, 0, 0);
#pragma unroll
    for (int j = 0; j < 4; ++j)
#pragma unroll
      for (int r = 0; r < 4; ++r)
        Ob[(size_t)(m + rg4 + r) * C_ + j * 16 + col] = fmaxf(acc[j][r], 0.f);
  }
}

extern "C" void kernel_launch(void* const* d_in, const int* in_sizes, int n_in,
                              void* d_out, int out_size, void* d_ws, size_t ws_size,
                              hipStream_t stream) {
  const float* X  = (const float*)d_in[0];  // [16,512,32,24]
  const float* SA = (const float*)d_in[1];  // [16,512,512]
  const float* CH = (const float*)d_in[2];  // [3,512,512]
  const float* TH = (const float*)d_in[3];  // [3,32,64]
  float* Out = (float*)d_out;               // [24,16,512,64]

  // ws partition (bytes): R2 37,748,736 | Xt2 12,582,912 | At 25,165,824
  char* ws = (char*)d_ws;
  ushort* R2  = (ushort*)(ws);
  ushort* Xt2 = (ushort*)(ws + 37748736);
  ushort* At  = (ushort*)(ws + 37748736 + 12582912);

  prep<<<dim3(1536), 256, 0, stream>>>(X, SA, CH, Xt2, At);
  stage1<<<dim3(768), 256, 0, stream>>>(Xt2, At, R2);
  stage2<<<dim3(2, 24, 16), 256, 0, stream>>>(R2, TH, Out);
}

// Round 8
// 135.685 us; speedup vs baseline: 1.1993x; 1.0720x over previous
//
#include <hip/hip_runtime.h>
#include <hip/hip_bf16.h>

#define B_ 16
#define N_ 512
#define F_ 32
#define T_ 24
#define K_ 3
#define C_ 64
#define FT_ 768   // F_*T_
#define KF_ 96    // K_*F_
#define KFP 104   // padded kf stride in P (bank-conflict-free: 52 dw ≡ 20 mod 32)

typedef __attribute__((ext_vector_type(8))) short bf16x8;
typedef __attribute__((ext_vector_type(4))) float f32x4;

static __device__ __forceinline__ ushort f2b(float x) {
  uint u = __float_as_uint(x);
  return (ushort)((u + 0x7fffu + ((u >> 16) & 1u)) >> 16);
}
static __device__ __forceinline__ uint pk2(float a, float b) {
  return (uint)f2b(a) | ((uint)f2b(b) << 16);
}

#define GLOAD_LDS16(g, l)                                                     \
  __builtin_amdgcn_global_load_lds(                                           \
      (const __attribute__((address_space(1))) void*)(g),                     \
      (__attribute__((address_space(3))) void*)(l), 16, 0, 0)

// ------- prep: X-transpose (0..767) + A-build (768..1535) + Theta (1536) ----
#define XP_PAD 260
__global__ __launch_bounds__(256) void prep(const float* __restrict__ X,
                                            const float* __restrict__ SA,
                                            const float* __restrict__ CH,
                                            const float* __restrict__ TH,
                                            ushort* __restrict__ Xt2,
                                            ushort* __restrict__ At,
                                            ushort* __restrict__ Th2) {
  __shared__ ushort L[32 * XP_PAD];
  const int bid = blockIdx.x;
  const int tid = threadIdx.x;
  if (bid < 768) {
    // Xt2[b][t*32+f][n] = X[b][n][f*24+t]
    const int local = bid % 48;
    const int b = bid / 48;
    const int n0 = (local & 15) * 32;
    const int fg = local >> 4;             // t in [fg*8, fg*8+8)
    const float* Xp = X + ((size_t)b * N_ + n0) * FT_ + fg * 8;
#pragma unroll
    for (int it = 0; it < 8; ++it) {
      int c = tid + it * 256;
      int row = c >> 6, rem = c & 63;
      int f = rem >> 1, half = rem & 1;
      float4 v = *(const float4*)(Xp + (size_t)row * FT_ + f * 24 + half * 4);
      uint2 p; p.x = pk2(v.x, v.y); p.y = pk2(v.z, v.w);
      *(uint2*)&L[row * XP_PAD + f * 8 + half * 4] = p;
    }
    __syncthreads();
    const int ft2 = fg * 256 + tid;
    const int f = tid & 31, dt = tid >> 5;
    ushort a[32];
#pragma unroll
    for (int r = 0; r < 32; ++r) a[r] = L[r * XP_PAD + f * 8 + dt];
    uint w[16];
#pragma unroll
    for (int q = 0; q < 16; ++q) w[q] = (uint)a[2 * q] | ((uint)a[2 * q + 1] << 16);
    ushort* op = Xt2 + ((size_t)b * FT_ + ft2) * N_ + n0;
#pragma unroll
    for (int q = 0; q < 4; ++q) {
      uint4 v; v.x = w[4*q]; v.y = w[4*q+1]; v.z = w[4*q+2]; v.w = w[4*q+3];
      *((uint4*)op + q) = v;
    }
  } else if (bid < 1536) {
    // At[k*16+b][m][n] = CH[k][n][m] * SA[b][n][m]
    const int a = bid - 768;
    const int kb = a >> 4;
    const int k = kb >> 4, b = kb & 15;
    const int sub = a & 15;
    const int ml = (tid & 15) * 4, nl = (tid >> 4) * 4;
#pragma unroll
    for (int c = 0; c < 4; ++c) {
      const int tile = sub * 4 + c;
      const int m0 = (tile & 7) * 64, n0 = (tile >> 3) * 64;
      const float* cp = CH + ((size_t)k * N_ + n0 + nl) * N_ + m0 + ml;
      const float* sp = SA + ((size_t)b * N_ + n0 + nl) * N_ + m0 + ml;
      float4 p[4];
#pragma unroll
      for (int q = 0; q < 4; ++q) {
        float4 cv = *(const float4*)(cp + (size_t)q * N_);
        float4 sv = *(const float4*)(sp + (size_t)q * N_);
        p[q] = make_float4(cv.x * sv.x, cv.y * sv.y, cv.z * sv.z, cv.w * sv.w);
      }
      ushort* ob = At + (size_t)kb * N_ * N_ + (size_t)(m0 + ml) * N_ + n0 + nl;
#pragma unroll
      for (int s = 0; s < 4; ++s) {
        uint2 w;
        w.x = pk2(((const float*)&p[0])[s], ((const float*)&p[1])[s]);
        w.y = pk2(((const float*)&p[2])[s], ((const float*)&p[3])[s]);
        *(uint2*)(ob + (size_t)s * N_) = w;
      }
    }
  } else {
    // Th2[o][kf] = bf16(TH[kf][o])
    for (int i = tid; i < C_ * KF_; i += 256) {
      int o = i / KF_, kf = i - o * KF_;
      Th2[i] = f2b(TH[(size_t)kf * C_ + o]);
    }
  }
}

// ------- fused stage: GEMM1 (k-folded, n-contraction) + in-LDS GEMM2 + ReLU --
// block: 128 ft (4 t x 32 f) x 64 m x 3 k; then out[t, b, m0:m0+64, :] direct.
__global__ __launch_bounds__(256, 3) void stage1(const ushort* __restrict__ Xt2,
                                                 const ushort* __restrict__ At,
                                                 const ushort* __restrict__ Th2,
                                                 float* __restrict__ Out) {
  __shared__ __align__(16) char smem[4 * 64 * KFP * 2];  // 53248 B
  ushort* Abuf = (ushort*)smem;                // 128x64 bf16 = 16 KB
  ushort* Bbuf = (ushort*)(smem + 16384);      // 3 x 64x64 bf16 = 24 KB
  ushort* P    = (ushort*)smem;                // [4t][64m][KFP] (reuse after loop)

  const int bid = blockIdx.x;
  const int logical = (bid & 7) * 96 + (bid >> 3);   // XCD-chunked, bijective
  const int b = logical / 48;
  const int tile = logical % 48;
  const int ft0 = (tile >> 3) * 128;
  const int m0 = (tile & 7) * 64;
  const int tid = threadIdx.x, lane = tid & 63, wid = tid >> 6;
  const int wft = (wid >> 1) * 64, wm = (wid & 1) * 32;
  const int srow = lane >> 3;
  const int scolS = ((lane & 7) * 16) ^ (srow << 4);

  const char* Xbase = (const char*)(Xt2 + ((size_t)b * FT_ + ft0) * N_);
  const char* Bk[3];
#pragma unroll
  for (int kq = 0; kq < 3; ++kq)
    Bk[kq] = (const char*)(At + ((size_t)(kq * 16 + b) * N_ + m0) * N_);

  f32x4 acc[3][4][2];
#pragma unroll
  for (int kq = 0; kq < 3; ++kq)
#pragma unroll
    for (int i = 0; i < 4; ++i)
#pragma unroll
      for (int j = 0; j < 2; ++j) acc[kq][i][j] = (f32x4){0.f, 0.f, 0.f, 0.f};

  for (int nb = 0; nb < 8; ++nb) {
    __syncthreads();
#pragma unroll
    for (int c = 0; c < 4; ++c) {                     // A: 16 segs of 1KB
      const int s = wid * 4 + c;
      const size_t go = (size_t)(s * 8 + srow) * 1024 + nb * 128 + scolS;
      GLOAD_LDS16(Xbase + go, (char*)Abuf + s * 1024);
    }
#pragma unroll
    for (int c = 0; c < 6; ++c) {                     // B: 3 x 8 segs of 1KB, 8KB per k
      const int idx = wid * 6 + c;
      const int kq = idx >> 3, seg = idx & 7;
      const size_t go = (size_t)(seg * 8 + srow) * 1024 + nb * 128 + scolS;
      GLOAD_LDS16(Bk[kq] + go, (char*)Bbuf + kq * 8192 + seg * 1024);
    }
    __syncthreads();
#pragma unroll
    for (int kk = 0; kk < 2; ++kk) {
      const int cb = (kk * 64 + (lane >> 4) * 16) ^ ((lane & 7) << 4);
      bf16x8 af[4];
#pragma unroll
      for (int i = 0; i < 4; ++i)
        af[i] = *(const bf16x8*)((const char*)Abuf + (wft + i * 16 + (lane & 15)) * 128 + cb);
#pragma unroll
      for (int kq = 0; kq < 3; ++kq) {
        bf16x8 bf[2];
#pragma unroll
        for (int j = 0; j < 2; ++j)
          bf[j] = *(const bf16x8*)((const char*)Bbuf + kq * 8192 + (wm + j * 16 + (lane & 15)) * 128 + cb);
#pragma unroll
        for (int i = 0; i < 4; ++i)
#pragma unroll
          for (int j = 0; j < 2; ++j)
            acc[kq][i][j] = __builtin_amdgcn_mfma_f32_16x16x32_bf16(af[i], bf[j], acc[kq][i][j], 0, 0, 0);
      }
    }
  }

  // ---- epilogue GEMM2: P[t][m][kf] = bf16(acc); out = relu(P x Th2^T) ----
  const int col = lane & 15, g = lane >> 4, rg4 = g * 4;
  __syncthreads();                        // staging buffers dead; safe to reuse as P
#pragma unroll
  for (int kq = 0; kq < 3; ++kq)
#pragma unroll
    for (int i = 0; i < 4; ++i) {
      const int ftl = wft + i * 16 + rg4;
      const int tl = ftl >> 5, f0 = ftl & 31;   // 4 regs = f0..f0+3, same t
#pragma unroll
      for (int j = 0; j < 2; ++j) {
        const int m = wm + j * 16 + col;
        uint2 w;
        w.x = pk2(acc[kq][i][j][0], acc[kq][i][j][1]);
        w.y = pk2(acc[kq][i][j][2], acc[kq][i][j][3]);
        *(uint2*)&P[(size_t)(tl * 64 + m) * KFP + kq * 32 + f0] = w;
      }
    }
  __syncthreads();

  bf16x8 bq[3][4];                        // Th2[o = j2*16+col][kf = kc*32+g*8..+8]
#pragma unroll
  for (int kc = 0; kc < 3; ++kc)
#pragma unroll
    for (int j2 = 0; j2 < 4; ++j2)
      bq[kc][j2] = *(const bf16x8*)(Th2 + (size_t)(j2 * 16 + col) * KF_ + kc * 32 + g * 8);

  f32x4 acc2[4][4];
#pragma unroll
  for (int i2 = 0; i2 < 4; ++i2)
#pragma unroll
    for (int j2 = 0; j2 < 4; ++j2) acc2[i2][j2] = (f32x4){0.f, 0.f, 0.f, 0.f};

#pragma unroll
  for (int kc = 0; kc < 3; ++kc)
#pragma unroll
    for (int i2 = 0; i2 < 4; ++i2) {
      const bf16x8 a2 = *(const bf16x8*)&P[(size_t)(wid * 64 + i2 * 16 + col) * KFP + kc * 32 + g * 8];
#pragma unroll
      for (int j2 = 0; j2 < 4; ++j2)
        acc2[i2][j2] = __builtin_amdgcn_mfma_f32_16x16x32_bf16(a2, bq[kc][j2], acc2[i2][j2], 0, 0, 0);
    }

  // D2: row = m (g*4+r), col = o; wave wid owns t = t0 + wid
  const int t = (tile >> 3) * 4 + wid;
  float* Ob = Out + ((size_t)(t * B_ + b) * N_ + m0) * C_;
#pragma unroll
  for (int i2 = 0; i2 < 4; ++i2)
#pragma unroll
    for (int j2 = 0; j2 < 4; ++j2)
#pragma unroll
      for (int r = 0; r < 4; ++r)
        Ob[(size_t)(i2 * 16 + rg4 + r) * C_ + j2 * 16 + col] = fmaxf(acc2[i2][j2][r], 0.f);
}

extern "C" void kernel_launch(void* const* d_in, const int* in_sizes, int n_in,
                              void* d_out, int out_size, void* d_ws, size_t ws_size,
                              hipStream_t stream) {
  const float* X  = (const float*)d_in[0];  // [16,512,32,24]
  const float* SA = (const float*)d_in[1];  // [16,512,512]
  const float* CH = (const float*)d_in[2];  // [3,512,512]
  const float* TH = (const float*)d_in[3];  // [3,32,64]
  float* Out = (float*)d_out;               // [24,16,512,64]

  // ws partition (bytes): Xt2 12,582,912 | At 25,165,824 | Th2 12,288
  char* ws = (char*)d_ws;
  ushort* Xt2 = (ushort*)(ws);
  ushort* At  = (ushort*)(ws + 12582912);
  ushort* Th2 = (ushort*)(ws + 12582912 + 25165824);

  prep<<<dim3(1537), 256, 0, stream>>>(X, SA, CH, TH, Xt2, At, Th2);
  stage1<<<dim3(768), 256, 0, stream>>>(Xt2, At, Th2, Out);
}